// Round 8
// baseline (78.713 us; speedup 1.0000x reference)
//
#include <hip/hip_runtime.h>
#include <math.h>

// Input: features [32, 512, 64, 64] f32. Output: 14 f32 SPP maxes (k=1,2,3).
//
// Single fused kernel + tiny counter-memset node (last-block completion).
//
// spp_fused: 1024 blocks x 1024 threads; block b reduces images [16b,16b+16)
// over the image axis (thread t owns positions 4t..4t+3; 4 independent fmax
// chains, full unroll, coalesced 16B/lane plain loads -- nt measured -2us).
// Positions staged in LDS (sm[h*64+w]); wave q (q<14) reduces bin q with
// compile-time trip counts (round 7: runtime-count serial ds_read chain cost
// 5.7 us). Per-block partial -> P2[q*1024 + b] via AGENT-scoped store
// (device-coherent; per-XCD L2 is not cross-coherent for plain stores).
//
// Completion: __syncthreads() drains each wave's stores (compiler emits
// s_waitcnt vmcnt(0) before s_barrier), then t0 increments a 2-LEVEL counter
// tree: 8 level-1 counters spaced 256 B apart (<=128 same-line atomics each;
// round 3 measured ~8 ns per same-line atomic -> ~1 us total, vs 8 us for a
// single counter), group-last increments level-2; the globally-last block
// re-reads P2 with agent loads and writes d_out. Counters are zeroed each
// call by hipMemsetAsync (self-reset can't survive the one-time 0xAA poison).

#define IMG_F4 1024          // 64*64/4 float4s per image (16 KiB)
#define IMGS_PER_BLOCK 16
#define MAIN_BLOCKS 1024     // 16384 images / 16
#define NBIN 14
#define NGRP 8
#define GRP_SIZE (MAIN_BLOCKS / NGRP)     // 128

#define P2_FLOATS (NBIN * MAIN_BLOCKS)    // 14336
#define CTR_BASE_BYTES (P2_FLOATS * 4)    // 57344: counters live after P2
#define CTR_STRIDE_INT 64                 // 256 B spacing -> separate lines
#define CTR2_IDX (NGRP * CTR_STRIDE_INT)  // level-2 counter
#define MEMSET_BYTES ((NGRP * CTR_STRIDE_INT + 1) * 4 + 60)   // covers ctr1[8]+ctr2

__device__ __forceinline__ void fmax4(float4& m, const float4 v) {
    m.x = fmaxf(m.x, v.x);
    m.y = fmaxf(m.y, v.y);
    m.z = fmaxf(m.z, v.z);
    m.w = fmaxf(m.w, v.w);
}

__global__ __launch_bounds__(1024, 8)
void spp_fused(const float4* __restrict__ in, float* __restrict__ P2,
               int* __restrict__ ctrs, float* __restrict__ out) {
    const int t = threadIdx.x;
    const long long base = (long long)blockIdx.x * (IMGS_PER_BLOCK * IMG_F4) + t;

    // image-axis reduction: 4 independent chains, full unroll
    float4 m0 = in[base + 0 * IMG_F4];
    float4 m1 = in[base + 1 * IMG_F4];
    float4 m2 = in[base + 2 * IMG_F4];
    float4 m3 = in[base + 3 * IMG_F4];
    #pragma unroll
    for (int img = 4; img < IMGS_PER_BLOCK; img += 4) {
        fmax4(m0, in[base + (long long)(img + 0) * IMG_F4]);
        fmax4(m1, in[base + (long long)(img + 1) * IMG_F4]);
        fmax4(m2, in[base + (long long)(img + 2) * IMG_F4]);
        fmax4(m3, in[base + (long long)(img + 3) * IMG_F4]);
    }
    fmax4(m0, m1);
    fmax4(m2, m3);
    fmax4(m0, m2);

    // stage per-position maxes: sm[4t + e] == sm[h*64 + w]
    __shared__ float sm[4096];
    __shared__ int sLast;
    *(float4*)&sm[t * 4] = m0;
    __syncthreads();

    const int q = t >> 6;     // wave id = bin id
    const int l = t & 63;     // lane id = w coordinate
    if (q < NBIN) {
        float best = -INFINITY;
        if (q == 0) {                       // k=1: whole map, 64 rows
            float b0 = -INFINITY, b1 = -INFINITY, b2 = -INFINITY, b3 = -INFINITY;
            #pragma unroll
            for (int i = 0; i < 64; i += 4) {
                b0 = fmaxf(b0, sm[(i + 0) * 64 + l]);
                b1 = fmaxf(b1, sm[(i + 1) * 64 + l]);
                b2 = fmaxf(b2, sm[(i + 2) * 64 + l]);
                b3 = fmaxf(b3, sm[(i + 3) * 64 + l]);
            }
            best = fmaxf(fmaxf(b0, b1), fmaxf(b2, b3));
        } else if (q < 5) {                 // k=2: 32 rows, w-mask by half
            const int b = q - 1;
            const int rs = (b >> 1) * 32;
            float b0 = -INFINITY, b1 = -INFINITY, b2 = -INFINITY, b3 = -INFINITY;
            #pragma unroll
            for (int i = 0; i < 32; i += 4) {
                b0 = fmaxf(b0, sm[(rs + i + 0) * 64 + l]);
                b1 = fmaxf(b1, sm[(rs + i + 1) * 64 + l]);
                b2 = fmaxf(b2, sm[(rs + i + 2) * 64 + l]);
                b3 = fmaxf(b3, sm[(rs + i + 3) * 64 + l]);
            }
            best = fmaxf(fmaxf(b0, b1), fmaxf(b2, b3));
            if ((l >> 5) != (b & 1)) best = -INFINITY;
        } else {                            // k=3: 21 rows, col 63 + outside excluded
            const int b = q - 5;
            const int rs = (b / 3) * 21;
            float b0 = -INFINITY, b1 = -INFINITY, b2 = -INFINITY;
            #pragma unroll
            for (int i = 0; i < 21; i += 3) {
                b0 = fmaxf(b0, sm[(rs + i + 0) * 64 + l]);
                b1 = fmaxf(b1, sm[(rs + i + 1) * 64 + l]);
                b2 = fmaxf(b2, sm[(rs + i + 2) * 64 + l]);
            }
            best = fmaxf(b0, fmaxf(b1, b2));
            if (!(l < 63 && (l / 21) == (b % 3))) best = -INFINITY;
        }

        #pragma unroll
        for (int off = 32; off > 0; off >>= 1)
            best = fmaxf(best, __shfl_down(best, off, 64));

        if (l == 0)
            __hip_atomic_store(&P2[q * MAIN_BLOCKS + blockIdx.x], best,
                               __ATOMIC_RELAXED, __HIP_MEMORY_SCOPE_AGENT);
    }

    // ---- completion counting (all 16 waves reach both barriers) ----
    __syncthreads();   // each wave drains vmcnt before s_barrier -> P2 visible
    if (t == 0) {
        int last = 0;
        const int g = blockIdx.x & (NGRP - 1);
        int o1 = __hip_atomic_fetch_add(&ctrs[g * CTR_STRIDE_INT], 1,
                                        __ATOMIC_ACQ_REL, __HIP_MEMORY_SCOPE_AGENT);
        if (o1 == GRP_SIZE - 1) {
            int o2 = __hip_atomic_fetch_add(&ctrs[CTR2_IDX], 1,
                                            __ATOMIC_ACQ_REL, __HIP_MEMORY_SCOPE_AGENT);
            last = (o2 == NGRP - 1);
        }
        sLast = last;
    }
    __syncthreads();

    if (sLast && q < NBIN) {    // globally-last block folds P2 -> out
        float best = -INFINITY;
        #pragma unroll
        for (int j = 0; j < MAIN_BLOCKS; j += 64)
            best = fmaxf(best, __hip_atomic_load(&P2[q * MAIN_BLOCKS + j + l],
                         __ATOMIC_RELAXED, __HIP_MEMORY_SCOPE_AGENT));
        #pragma unroll
        for (int off = 32; off > 0; off >>= 1)
            best = fmaxf(best, __shfl_down(best, off, 64));
        if (l == 0) out[q] = best;
    }
}

extern "C" void kernel_launch(void* const* d_in, const int* in_sizes, int n_in,
                              void* d_out, int out_size, void* d_ws, size_t ws_size,
                              hipStream_t stream) {
    const float4* in = (const float4*)d_in[0];
    float* out = (float*)d_out;
    float* P2 = (float*)d_ws;                               // 56 KiB partials
    int* ctrs = (int*)((char*)d_ws + CTR_BASE_BYTES);       // counter tree

    hipMemsetAsync((char*)d_ws + CTR_BASE_BYTES, 0, MEMSET_BYTES, stream);
    spp_fused<<<MAIN_BLOCKS, 1024, 0, stream>>>(in, P2, ctrs, out);
}

// Round 9
// 47.631 us; speedup vs baseline: 1.6525x; 1.6525x over previous
//
#include <hip/hip_runtime.h>
#include <math.h>

// Input: features [32, 512, 64, 64] f32. Output: 14 f32 SPP maxes (k=1,2,3).
//
// Round-7 proven two-kernel structure (49.5 us), single-variable change:
// 2048 blocks x 8 images (was 1024 x 16) -> 4 co-resident rounds instead of
// 2, so only the last quarter's LDS/bin tails are exposed at stream end and
// block completion staggers (backfill). Round 8's fused last-block variant
// REGRESSED 49.5 -> 78.7 us (in-kernel completion atomics + extra graph node
// perturb the stream) -- reverted.
//
// spp_main: block b reduces images [8b, 8b+8) over the image axis (thread t
// owns positions 4t..4t+3; 4 independent fmax chains, full unroll, coalesced
// 16B/lane plain loads -- nt loads measured -2us). Positions staged in LDS
// (sm[h*64+w]); wave q (q<14) reduces bin q with compile-time trip counts
// (runtime-count serial ds_read chain measured +5.7 us). One plain float
// store per (block, bin), transposed: P2[q*2048 + b]. No atomics on shared
// lines (round 3: -58 us).
//
// spp_final: 1 block; wave q folds P2[q*2048 .. +2048) via float4 loads.

#define IMG_F4 1024          // 64*64/4 float4s per image (16 KiB)
#define IMGS_PER_BLOCK 8
#define MAIN_BLOCKS 2048     // 16384 images / 8
#define NBIN 14

__device__ __forceinline__ void fmax4(float4& m, const float4 v) {
    m.x = fmaxf(m.x, v.x);
    m.y = fmaxf(m.y, v.y);
    m.z = fmaxf(m.z, v.z);
    m.w = fmaxf(m.w, v.w);
}

__global__ __launch_bounds__(1024, 8)
void spp_main(const float4* __restrict__ in, float* __restrict__ P2) {
    const int t = threadIdx.x;
    const long long base = (long long)blockIdx.x * (IMGS_PER_BLOCK * IMG_F4) + t;

    // image-axis reduction: 4 independent chains, full unroll (8 images)
    float4 m0 = in[base + 0 * IMG_F4];
    float4 m1 = in[base + 1 * IMG_F4];
    float4 m2 = in[base + 2 * IMG_F4];
    float4 m3 = in[base + 3 * IMG_F4];
    fmax4(m0, in[base + 4 * IMG_F4]);
    fmax4(m1, in[base + 5 * IMG_F4]);
    fmax4(m2, in[base + 6 * IMG_F4]);
    fmax4(m3, in[base + 7 * IMG_F4]);
    fmax4(m0, m1);
    fmax4(m2, m3);
    fmax4(m0, m2);

    // stage per-position maxes: sm[4t + e] == sm[h*64 + w]
    __shared__ float sm[4096];
    *(float4*)&sm[t * 4] = m0;
    __syncthreads();

    const int q = t >> 6;     // wave id = bin id
    const int l = t & 63;     // lane id = w coordinate
    if (q < NBIN) {
        float best = -INFINITY;
        if (q == 0) {                       // k=1: whole map, 64 rows
            float b0 = -INFINITY, b1 = -INFINITY, b2 = -INFINITY, b3 = -INFINITY;
            #pragma unroll
            for (int i = 0; i < 64; i += 4) {
                b0 = fmaxf(b0, sm[(i + 0) * 64 + l]);
                b1 = fmaxf(b1, sm[(i + 1) * 64 + l]);
                b2 = fmaxf(b2, sm[(i + 2) * 64 + l]);
                b3 = fmaxf(b3, sm[(i + 3) * 64 + l]);
            }
            best = fmaxf(fmaxf(b0, b1), fmaxf(b2, b3));
        } else if (q < 5) {                 // k=2: 32 rows, w-mask by half
            const int b = q - 1;
            const int rs = (b >> 1) * 32;
            float b0 = -INFINITY, b1 = -INFINITY, b2 = -INFINITY, b3 = -INFINITY;
            #pragma unroll
            for (int i = 0; i < 32; i += 4) {
                b0 = fmaxf(b0, sm[(rs + i + 0) * 64 + l]);
                b1 = fmaxf(b1, sm[(rs + i + 1) * 64 + l]);
                b2 = fmaxf(b2, sm[(rs + i + 2) * 64 + l]);
                b3 = fmaxf(b3, sm[(rs + i + 3) * 64 + l]);
            }
            best = fmaxf(fmaxf(b0, b1), fmaxf(b2, b3));
            if ((l >> 5) != (b & 1)) best = -INFINITY;
        } else {                            // k=3: 21 rows, col 63 + outside excluded
            const int b = q - 5;
            const int rs = (b / 3) * 21;
            float b0 = -INFINITY, b1 = -INFINITY, b2 = -INFINITY;
            #pragma unroll
            for (int i = 0; i < 21; i += 3) {
                b0 = fmaxf(b0, sm[(rs + i + 0) * 64 + l]);
                b1 = fmaxf(b1, sm[(rs + i + 1) * 64 + l]);
                b2 = fmaxf(b2, sm[(rs + i + 2) * 64 + l]);
            }
            best = fmaxf(b0, fmaxf(b1, b2));
            if (!(l < 63 && (l / 21) == (b % 3))) best = -INFINITY;
        }

        #pragma unroll
        for (int off = 32; off > 0; off >>= 1)
            best = fmaxf(best, __shfl_down(best, off, 64));

        if (l == 0) P2[q * MAIN_BLOCKS + blockIdx.x] = best;   // transposed
    }
}

__global__ __launch_bounds__(1024)
void spp_final(const float4* __restrict__ P2v, float* __restrict__ out) {
    const int q = threadIdx.x >> 6;
    const int l = threadIdx.x & 63;
    if (q >= NBIN) return;

    const int row = q * (MAIN_BLOCKS / 4);   // float4 row base
    float4 m = P2v[row + l];
    #pragma unroll
    for (int j = 64; j < MAIN_BLOCKS / 4; j += 64)
        fmax4(m, P2v[row + j + l]);          // coalesced 16B/lane
    float best = fmaxf(fmaxf(m.x, m.y), fmaxf(m.z, m.w));

    #pragma unroll
    for (int off = 32; off > 0; off >>= 1)
        best = fmaxf(best, __shfl_down(best, off, 64));

    if (l == 0) out[q] = best;
}

extern "C" void kernel_launch(void* const* d_in, const int* in_sizes, int n_in,
                              void* d_out, int out_size, void* d_ws, size_t ws_size,
                              hipStream_t stream) {
    const float4* in = (const float4*)d_in[0];
    float* out = (float*)d_out;
    float* P2 = (float*)d_ws;   // 14*2048 floats = 112 KiB scratch

    spp_main<<<MAIN_BLOCKS, 1024, 0, stream>>>(in, P2);
    spp_final<<<1, 1024, 0, stream>>>((const float4*)P2, out);
}

// Round 10
// 45.776 us; speedup vs baseline: 1.7195x; 1.0405x over previous
//
#include <hip/hip_runtime.h>
#include <math.h>

// Input: features [32, 512, 64, 64] f32. Output: 14 f32 SPP maxes (k=1,2,3).
//
// Ladder so far: 95.9 (global atomicMax scratch) -> 57.5 (block-local LDS
// bins + plain stores) -> [115.7 fused same-line atomics REVERTED]
// -> [59.6 nontemporal loads REVERTED] -> 55.2 (1024 blocks: tail overlap)
// -> 49.5 (compile-time bin trip counts) -> [78.7 in-kernel completion
// REVERTED] -> 47.6 (2048 blocks: more tail overlap).
//
// This round: 4096 blocks x 4 images (8 co-resident rounds -> exposed tail
// halves again) + spp_final parallelized to 14 blocks (one bin each,
// float4-coalesced) instead of one latency-bound 1024-thread block.
//
// spp_main: block b reduces images [4b, 4b+4) (thread t owns positions
// 4t..4t+3; independent fmax chains, coalesced 16B/lane plain loads).
// Positions staged in LDS (sm[h*64+w]); wave q (q<14) reduces bin q with
// compile-time trip counts; one plain float store per (block, bin),
// transposed: P2[q*4096 + b]. No same-line atomics anywhere.

#define IMG_F4 1024          // 64*64/4 float4s per image (16 KiB)
#define IMGS_PER_BLOCK 4
#define MAIN_BLOCKS 4096     // 16384 images / 4
#define NBIN 14

__device__ __forceinline__ void fmax4(float4& m, const float4 v) {
    m.x = fmaxf(m.x, v.x);
    m.y = fmaxf(m.y, v.y);
    m.z = fmaxf(m.z, v.z);
    m.w = fmaxf(m.w, v.w);
}

__global__ __launch_bounds__(1024, 8)
void spp_main(const float4* __restrict__ in, float* __restrict__ P2) {
    const int t = threadIdx.x;
    const long long base = (long long)blockIdx.x * (IMGS_PER_BLOCK * IMG_F4) + t;

    // image-axis reduction: 4 independent loads, pairwise fold
    float4 m0 = in[base + 0 * IMG_F4];
    float4 m1 = in[base + 1 * IMG_F4];
    float4 m2 = in[base + 2 * IMG_F4];
    float4 m3 = in[base + 3 * IMG_F4];
    fmax4(m0, m1);
    fmax4(m2, m3);
    fmax4(m0, m2);

    // stage per-position maxes: sm[4t + e] == sm[h*64 + w]
    __shared__ float sm[4096];
    *(float4*)&sm[t * 4] = m0;
    __syncthreads();

    const int q = t >> 6;     // wave id = bin id
    const int l = t & 63;     // lane id = w coordinate
    if (q < NBIN) {
        float best = -INFINITY;
        if (q == 0) {                       // k=1: whole map, 64 rows
            float b0 = -INFINITY, b1 = -INFINITY, b2 = -INFINITY, b3 = -INFINITY;
            #pragma unroll
            for (int i = 0; i < 64; i += 4) {
                b0 = fmaxf(b0, sm[(i + 0) * 64 + l]);
                b1 = fmaxf(b1, sm[(i + 1) * 64 + l]);
                b2 = fmaxf(b2, sm[(i + 2) * 64 + l]);
                b3 = fmaxf(b3, sm[(i + 3) * 64 + l]);
            }
            best = fmaxf(fmaxf(b0, b1), fmaxf(b2, b3));
        } else if (q < 5) {                 // k=2: 32 rows, w-mask by half
            const int b = q - 1;
            const int rs = (b >> 1) * 32;
            float b0 = -INFINITY, b1 = -INFINITY, b2 = -INFINITY, b3 = -INFINITY;
            #pragma unroll
            for (int i = 0; i < 32; i += 4) {
                b0 = fmaxf(b0, sm[(rs + i + 0) * 64 + l]);
                b1 = fmaxf(b1, sm[(rs + i + 1) * 64 + l]);
                b2 = fmaxf(b2, sm[(rs + i + 2) * 64 + l]);
                b3 = fmaxf(b3, sm[(rs + i + 3) * 64 + l]);
            }
            best = fmaxf(fmaxf(b0, b1), fmaxf(b2, b3));
            if ((l >> 5) != (b & 1)) best = -INFINITY;
        } else {                            // k=3: 21 rows, col 63 + outside excluded
            const int b = q - 5;
            const int rs = (b / 3) * 21;
            float b0 = -INFINITY, b1 = -INFINITY, b2 = -INFINITY;
            #pragma unroll
            for (int i = 0; i < 21; i += 3) {
                b0 = fmaxf(b0, sm[(rs + i + 0) * 64 + l]);
                b1 = fmaxf(b1, sm[(rs + i + 1) * 64 + l]);
                b2 = fmaxf(b2, sm[(rs + i + 2) * 64 + l]);
            }
            best = fmaxf(b0, fmaxf(b1, b2));
            if (!(l < 63 && (l / 21) == (b % 3))) best = -INFINITY;
        }

        #pragma unroll
        for (int off = 32; off > 0; off >>= 1)
            best = fmaxf(best, __shfl_down(best, off, 64));

        if (l == 0) P2[q * MAIN_BLOCKS + blockIdx.x] = best;   // transposed
    }
}

// 14 blocks, one bin each: 256 threads scan P2[q*4096 .. +4096) as float4.
__global__ __launch_bounds__(256)
void spp_final(const float4* __restrict__ P2v, float* __restrict__ out) {
    const int q = blockIdx.x;
    const int t = threadIdx.x;
    const int row = q * (MAIN_BLOCKS / 4);   // 1024 float4s per bin row

    float4 m = P2v[row + t];
    #pragma unroll
    for (int j = 256; j < MAIN_BLOCKS / 4; j += 256)
        fmax4(m, P2v[row + j + t]);          // coalesced 16B/lane
    float best = fmaxf(fmaxf(m.x, m.y), fmaxf(m.z, m.w));

    #pragma unroll
    for (int off = 32; off > 0; off >>= 1)
        best = fmaxf(best, __shfl_down(best, off, 64));

    __shared__ float sw[4];
    if ((t & 63) == 0) sw[t >> 6] = best;
    __syncthreads();
    if (t == 0)
        out[q] = fmaxf(fmaxf(sw[0], sw[1]), fmaxf(sw[2], sw[3]));
}

extern "C" void kernel_launch(void* const* d_in, const int* in_sizes, int n_in,
                              void* d_out, int out_size, void* d_ws, size_t ws_size,
                              hipStream_t stream) {
    const float4* in = (const float4*)d_in[0];
    float* out = (float*)d_out;
    float* P2 = (float*)d_ws;   // 14*4096 floats = 224 KiB scratch

    spp_main<<<MAIN_BLOCKS, 1024, 0, stream>>>(in, P2);
    spp_final<<<NBIN, 256, 0, stream>>>((const float4*)P2, out);
}

// Round 11
// 44.710 us; speedup vs baseline: 1.7605x; 1.0238x over previous
//
#include <hip/hip_runtime.h>
#include <math.h>

// Input: features [32, 512, 64, 64] f32. Output: 14 f32 SPP maxes (k=1,2,3).
//
// Ladder: 95.9 (atomicMax scratch) -> 57.5 (LDS bins + plain stores)
// -> [115.7 same-line atomics REV] -> [59.6 nt loads REV] -> 55.2 (1024 blk)
// -> 49.5 (compile-time bin trip counts) -> [78.7 in-kernel completion REV]
// -> 47.6 (2048 blk) -> 45.8 (4096 blk + 14-block parallel final).
// Block-count gains not diminishing (finer end-of-stream scheduling
// granularity keeps HBM saturated); tail-work budget check: 8192 blocks =
// 32 rounds/CU x ~381 cyc LDS work = ~5 us/CU, still overlapped under the
// ~42.6 us stream. This round: 8192 blocks x 2 images.
//
// spp_main: block b reduces images [2b, 2b+2) (thread t owns positions
// 4t..4t+3, coalesced 16B/lane plain loads). Per-position maxes staged in
// LDS (sm[h*64+w]); wave q (q<14) reduces bin q with compile-time trip
// counts; one plain float store per (block, bin), transposed:
// P2[q*8192 + b]. No same-line atomics anywhere.
//
// spp_final: 14 blocks (one bin each), 256 threads, float4-coalesced scan.

#define IMG_F4 1024          // 64*64/4 float4s per image (16 KiB)
#define IMGS_PER_BLOCK 2
#define MAIN_BLOCKS 8192     // 16384 images / 2
#define NBIN 14

__device__ __forceinline__ void fmax4(float4& m, const float4 v) {
    m.x = fmaxf(m.x, v.x);
    m.y = fmaxf(m.y, v.y);
    m.z = fmaxf(m.z, v.z);
    m.w = fmaxf(m.w, v.w);
}

__global__ __launch_bounds__(1024, 8)
void spp_main(const float4* __restrict__ in, float* __restrict__ P2) {
    const int t = threadIdx.x;
    const long long base = (long long)blockIdx.x * (IMGS_PER_BLOCK * IMG_F4) + t;

    // image-axis reduction: 2 independent loads, one fold
    float4 m0 = in[base + 0 * IMG_F4];
    float4 m1 = in[base + 1 * IMG_F4];
    fmax4(m0, m1);

    // stage per-position maxes: sm[4t + e] == sm[h*64 + w]
    __shared__ float sm[4096];
    *(float4*)&sm[t * 4] = m0;
    __syncthreads();

    const int q = t >> 6;     // wave id = bin id
    const int l = t & 63;     // lane id = w coordinate
    if (q < NBIN) {
        float best = -INFINITY;
        if (q == 0) {                       // k=1: whole map, 64 rows
            float b0 = -INFINITY, b1 = -INFINITY, b2 = -INFINITY, b3 = -INFINITY;
            #pragma unroll
            for (int i = 0; i < 64; i += 4) {
                b0 = fmaxf(b0, sm[(i + 0) * 64 + l]);
                b1 = fmaxf(b1, sm[(i + 1) * 64 + l]);
                b2 = fmaxf(b2, sm[(i + 2) * 64 + l]);
                b3 = fmaxf(b3, sm[(i + 3) * 64 + l]);
            }
            best = fmaxf(fmaxf(b0, b1), fmaxf(b2, b3));
        } else if (q < 5) {                 // k=2: 32 rows, w-mask by half
            const int b = q - 1;
            const int rs = (b >> 1) * 32;
            float b0 = -INFINITY, b1 = -INFINITY, b2 = -INFINITY, b3 = -INFINITY;
            #pragma unroll
            for (int i = 0; i < 32; i += 4) {
                b0 = fmaxf(b0, sm[(rs + i + 0) * 64 + l]);
                b1 = fmaxf(b1, sm[(rs + i + 1) * 64 + l]);
                b2 = fmaxf(b2, sm[(rs + i + 2) * 64 + l]);
                b3 = fmaxf(b3, sm[(rs + i + 3) * 64 + l]);
            }
            best = fmaxf(fmaxf(b0, b1), fmaxf(b2, b3));
            if ((l >> 5) != (b & 1)) best = -INFINITY;
        } else {                            // k=3: 21 rows, col 63 + outside excluded
            const int b = q - 5;
            const int rs = (b / 3) * 21;
            float b0 = -INFINITY, b1 = -INFINITY, b2 = -INFINITY;
            #pragma unroll
            for (int i = 0; i < 21; i += 3) {
                b0 = fmaxf(b0, sm[(rs + i + 0) * 64 + l]);
                b1 = fmaxf(b1, sm[(rs + i + 1) * 64 + l]);
                b2 = fmaxf(b2, sm[(rs + i + 2) * 64 + l]);
            }
            best = fmaxf(b0, fmaxf(b1, b2));
            if (!(l < 63 && (l / 21) == (b % 3))) best = -INFINITY;
        }

        #pragma unroll
        for (int off = 32; off > 0; off >>= 1)
            best = fmaxf(best, __shfl_down(best, off, 64));

        if (l == 0) P2[q * MAIN_BLOCKS + blockIdx.x] = best;   // transposed
    }
}

// 14 blocks, one bin each: 256 threads scan P2[q*8192 .. +8192) as float4.
__global__ __launch_bounds__(256)
void spp_final(const float4* __restrict__ P2v, float* __restrict__ out) {
    const int q = blockIdx.x;
    const int t = threadIdx.x;
    const int row = q * (MAIN_BLOCKS / 4);   // 2048 float4s per bin row

    float4 m = P2v[row + t];
    #pragma unroll
    for (int j = 256; j < MAIN_BLOCKS / 4; j += 256)
        fmax4(m, P2v[row + j + t]);          // coalesced 16B/lane
    float best = fmaxf(fmaxf(m.x, m.y), fmaxf(m.z, m.w));

    #pragma unroll
    for (int off = 32; off > 0; off >>= 1)
        best = fmaxf(best, __shfl_down(best, off, 64));

    __shared__ float sw[4];
    if ((t & 63) == 0) sw[t >> 6] = best;
    __syncthreads();
    if (t == 0)
        out[q] = fmaxf(fmaxf(sw[0], sw[1]), fmaxf(sw[2], sw[3]));
}

extern "C" void kernel_launch(void* const* d_in, const int* in_sizes, int n_in,
                              void* d_out, int out_size, void* d_ws, size_t ws_size,
                              hipStream_t stream) {
    const float4* in = (const float4*)d_in[0];
    float* out = (float*)d_out;
    float* P2 = (float*)d_ws;   // 14*8192 floats = 448 KiB scratch

    spp_main<<<MAIN_BLOCKS, 1024, 0, stream>>>(in, P2);
    spp_final<<<NBIN, 256, 0, stream>>>((const float4*)P2, out);
}